// Round 1
// 197.009 us; speedup vs baseline: 1.0156x; 1.0156x over previous
//
#include <hip/hip_runtime.h>
#include <stdint.h>

// Problem constants (B=2, L=2048, D=2048, E=8, Dg=256, k=2)
#define T_TOK 4096
#define DIM   2048
#define NEXP  8
#define DG    256
#define TOPK  2

// GEMM tiling: block tile 64(M) x 128(N), BKU=64, 4 waves of 32x64 each,
// double-buffered LDS with 1-deep prefetch (T3-minimal 2-phase).
#define BM 64
#define BN 128
#define BKU 64
#define NROWS  (T_TOK*TOPK + NEXP*BM)   // 8704 padded row capacity
#define NBLK_M (NROWS/BM)               // 136 M-blocks

typedef __attribute__((ext_vector_type(8))) short short8;
typedef __attribute__((ext_vector_type(4))) float f32x4;

static __device__ __forceinline__ short f2bf(float f) {
    union { float f; uint32_t u; } v{f};
    uint32_t r = v.u + 0x7fffu + ((v.u >> 16) & 1u);   // RNE
    return (short)(r >> 16);
}
static __device__ __forceinline__ float b2f(short s) {
    union { uint32_t u; float f; } v{((uint32_t)(unsigned short)s) << 16};
    return v.f;
}

#define GLD16(g, l) \
    __builtin_amdgcn_global_load_lds((const __attribute__((address_space(1))) void*)(g), \
                                     (__attribute__((address_space(3))) void*)(l), 16, 0, 0)

// ---------------------------------------------------------------------------
// Gate + x->bf16 fusion. One wave per token.
// ---------------------------------------------------------------------------
__global__ __launch_bounds__(256) void gate_kernel(const float* __restrict__ x,
                                                   const float* __restrict__ Wg,
                                                   int* __restrict__ gidx,
                                                   float* __restrict__ gval,
                                                   short* __restrict__ x_bf)
{
    int token = blockIdx.x * 4 + (threadIdx.x >> 6);
    int lane  = threadIdx.x & 63;
    const float4* xr = (const float4*)(x + (size_t)token * DIM);

    float4 xv[8];
#pragma unroll
    for (int i = 0; i < 8; i++) xv[i] = xr[lane + 64 * i];

    short4* xb = (short4*)(x_bf + (size_t)token * DIM);
#pragma unroll
    for (int i = 0; i < 8; i++) {
        short4 o;
        o.x = f2bf(xv[i].x); o.y = f2bf(xv[i].y);
        o.z = f2bf(xv[i].z); o.w = f2bf(xv[i].w);
        xb[lane + 64 * i] = o;
    }

    float acc[NEXP];
#pragma unroll
    for (int e = 0; e < NEXP; e++) {
        const float4* wr = (const float4*)(Wg + e * DIM);
        float a = 0.0f;
#pragma unroll
        for (int i = 0; i < 8; i++) {
            float4 w = wr[lane + 64 * i];
            a += xv[i].x * w.x + xv[i].y * w.y + xv[i].z * w.z + xv[i].w * w.w;
        }
        acc[e] = a;
    }

#pragma unroll
    for (int m = 1; m < 64; m <<= 1) {
#pragma unroll
        for (int e = 0; e < NEXP; e++) acc[e] += __shfl_xor(acc[e], m, 64);
    }

    if (lane == 0) {
        float sg[NEXP];
#pragma unroll
        for (int e = 0; e < NEXP; e++) sg[e] = 1.0f / (1.0f + expf(-acc[e]));
        int i0 = 0;
#pragma unroll
        for (int e = 1; e < NEXP; e++) if (sg[e] > sg[i0]) i0 = e;   // strict >: lowest index wins
        int i1 = (i0 == 0) ? 1 : 0;
#pragma unroll
        for (int e = 0; e < NEXP; e++) if (e != i0 && e != i1 && sg[e] > sg[i1]) i1 = e;
        gidx[2 * token + 0] = i0;
        gidx[2 * token + 1] = i1;
        gval[2 * token + 0] = sg[i0];
        gval[2 * token + 1] = sg[i1];
    }
}

// ---------------------------------------------------------------------------
// Weight fp32 -> bf16 (Wd and Wu in one launch).
// ---------------------------------------------------------------------------
__global__ __launch_bounds__(256) void convW_kernel(const float* __restrict__ Wd,
                                                    const float* __restrict__ Wu,
                                                    short* __restrict__ Wd_bf,
                                                    short* __restrict__ Wu_bf,
                                                    int n4)
{
    int i = blockIdx.x * 256 + threadIdx.x;
    const float* s; short* d; int j;
    if (i < n4)      { s = Wd; d = Wd_bf; j = i; }
    else             { s = Wu; d = Wu_bf; j = i - n4; if (j >= n4) return; }
    float4 v = ((const float4*)s)[j];
    short4 o;
    o.x = f2bf(v.x); o.y = f2bf(v.y); o.z = f2bf(v.z); o.w = f2bf(v.w);
    ((short4*)d)[j] = o;
}

// ---------------------------------------------------------------------------
// Bucket rows by expert (segments padded to BM).
// ---------------------------------------------------------------------------
__global__ __launch_bounds__(1024) void bucket_kernel(const int* __restrict__ gidx,
                                                      int* __restrict__ rowtok,
                                                      int* __restrict__ rowpos,
                                                      int* __restrict__ seg_off)
{
    __shared__ int cnt[NEXP];
    __shared__ int cur[NEXP];
    int tid = threadIdx.x;
    if (tid < NEXP) cnt[tid] = 0;
    __syncthreads();

    for (int t = tid; t < T_TOK; t += 1024) {
        atomicAdd(&cnt[gidx[2 * t + 0]], 1);
        atomicAdd(&cnt[gidx[2 * t + 1]], 1);
    }
    __syncthreads();

    if (tid == 0) {
        int o = 0;
        for (int e = 0; e < NEXP; e++) {
            seg_off[e] = o;
            cur[e] = o;
            o += ((cnt[e] + BM - 1) / BM) * BM;
        }
        seg_off[NEXP] = o;
    }
    __syncthreads();

    for (int r = tid; r < NROWS; r += 1024) rowtok[r] = -1;
    __syncthreads();

    for (int t = tid; t < T_TOK; t += 1024) {
        for (int s = 0; s < TOPK; s++) {
            int e = gidx[2 * t + s];
            int p = atomicAdd(&cur[e], 1);
            rowtok[p] = t;
            rowpos[2 * t + s] = p;
        }
    }
}

// ---------------------------------------------------------------------------
// Grouped GEMM (bf16 MFMA), double-buffered 2-phase pipeline:
//   prologue STAGE(buf0); per 64-wide K-tile: STAGE(next buf) issued BEFORE
//   compute of current buf; single __syncthreads() per tile (vmcnt drain is
//   exactly the next buffer's loads, hidden under 12 ds_read + 16 MFMA).
// LDS rows are 128 B (alias all 32 banks) -> chunk-XOR swizzle (chunk ^= row&7)
// applied on the GLOBAL source (linear LDS dest, per global_load_lds rules);
// fragment ds_read_b128 then lands 8 lanes on each 16 B chunk = balanced.
// ---------------------------------------------------------------------------
#define AS3 __attribute__((address_space(3)))

#define STAGE(B_) do { \
    GLD16(agA0, lA_##B_##_0); \
    GLD16(agA1, lA_##B_##_1); \
    GLD16(agB0, lB_##B_##_0); \
    GLD16(agB1, lB_##B_##_1); \
    GLD16(agB2, lB_##B_##_2); \
    GLD16(agB3, lB_##B_##_3); \
    agA0 += BKU; agA1 += BKU; \
    agB0 += BKU; agB1 += BKU; agB2 += BKU; agB3 += BKU; \
} while (0)

#define COMP(B_) do { \
    short8 a00 = *(const short8*)&As[B_][am0][c0]; \
    short8 a10 = *(const short8*)&As[B_][am1][c0]; \
    short8 b00 = *(const short8*)&Bs[B_][bn0][c0]; \
    short8 b10 = *(const short8*)&Bs[B_][bn1][c0]; \
    short8 b20 = *(const short8*)&Bs[B_][bn2][c0]; \
    short8 b30 = *(const short8*)&Bs[B_][bn3][c0]; \
    short8 a01 = *(const short8*)&As[B_][am0][c1]; \
    short8 a11 = *(const short8*)&As[B_][am1][c1]; \
    short8 b01 = *(const short8*)&Bs[B_][bn0][c1]; \
    short8 b11 = *(const short8*)&Bs[B_][bn1][c1]; \
    short8 b21 = *(const short8*)&Bs[B_][bn2][c1]; \
    short8 b31 = *(const short8*)&Bs[B_][bn3][c1]; \
    acc[0][0] = __builtin_amdgcn_mfma_f32_16x16x32_bf16(a00, b00, acc[0][0], 0, 0, 0); \
    acc[0][1] = __builtin_amdgcn_mfma_f32_16x16x32_bf16(a00, b10, acc[0][1], 0, 0, 0); \
    acc[0][2] = __builtin_amdgcn_mfma_f32_16x16x32_bf16(a00, b20, acc[0][2], 0, 0, 0); \
    acc[0][3] = __builtin_amdgcn_mfma_f32_16x16x32_bf16(a00, b30, acc[0][3], 0, 0, 0); \
    acc[1][0] = __builtin_amdgcn_mfma_f32_16x16x32_bf16(a10, b00, acc[1][0], 0, 0, 0); \
    acc[1][1] = __builtin_amdgcn_mfma_f32_16x16x32_bf16(a10, b10, acc[1][1], 0, 0, 0); \
    acc[1][2] = __builtin_amdgcn_mfma_f32_16x16x32_bf16(a10, b20, acc[1][2], 0, 0, 0); \
    acc[1][3] = __builtin_amdgcn_mfma_f32_16x16x32_bf16(a10, b30, acc[1][3], 0, 0, 0); \
    acc[0][0] = __builtin_amdgcn_mfma_f32_16x16x32_bf16(a01, b01, acc[0][0], 0, 0, 0); \
    acc[0][1] = __builtin_amdgcn_mfma_f32_16x16x32_bf16(a01, b11, acc[0][1], 0, 0, 0); \
    acc[0][2] = __builtin_amdgcn_mfma_f32_16x16x32_bf16(a01, b21, acc[0][2], 0, 0, 0); \
    acc[0][3] = __builtin_amdgcn_mfma_f32_16x16x32_bf16(a01, b31, acc[0][3], 0, 0, 0); \
    acc[1][0] = __builtin_amdgcn_mfma_f32_16x16x32_bf16(a11, b01, acc[1][0], 0, 0, 0); \
    acc[1][1] = __builtin_amdgcn_mfma_f32_16x16x32_bf16(a11, b11, acc[1][1], 0, 0, 0); \
    acc[1][2] = __builtin_amdgcn_mfma_f32_16x16x32_bf16(a11, b21, acc[1][2], 0, 0, 0); \
    acc[1][3] = __builtin_amdgcn_mfma_f32_16x16x32_bf16(a11, b31, acc[1][3], 0, 0, 0); \
} while (0)

template<int K, int Ntot>
__global__ __launch_bounds__(256) void gemm_kernel(const short* __restrict__ A,
                                                   const short* __restrict__ B,
                                                   const int* __restrict__ rowtok,
                                                   const int* __restrict__ seg_off,
                                                   short* __restrict__ C)
{
    __shared__ __align__(16) short As[2][BM][BKU];   // 16 KB
    __shared__ __align__(16) short Bs[2][BN][BKU];   // 32 KB

    int row0 = blockIdx.x * BM;
    int total = seg_off[NEXP];
    if (row0 >= total) return;
    int e = 0;
    while (row0 >= seg_off[e + 1]) ++e;   // BM-padded segments: block in one expert
    int n0 = blockIdx.y * BN;

    int tid = threadIdx.x;
    int w = tid >> 6, l = tid & 63;

    // ---- staging addresses: wave w covers 8 rows per 32-row round ----
    int srow = (w << 3) + (l >> 3);                 // 0..31
    int sc   = ((l & 7) ^ ((l >> 3) & 7)) << 3;     // swizzled source chunk (shorts)

    int ta0 = rowtok[row0 + srow];      if (ta0 < 0) ta0 = 0;
    int ta1 = rowtok[row0 + 32 + srow]; if (ta1 < 0) ta1 = 0;
    const short* agA0 = A + (size_t)ta0 * K + sc;
    const short* agA1 = A + (size_t)ta1 * K + sc;
    const short* be = B + (size_t)e * Ntot * K + (size_t)n0 * K;
    const short* agB0 = be + (size_t)(srow     ) * K + sc;
    const short* agB1 = be + (size_t)(srow + 32) * K + sc;
    const short* agB2 = be + (size_t)(srow + 64) * K + sc;
    const short* agB3 = be + (size_t)(srow + 96) * K + sc;

    auto lA_0_0 = (AS3 void*)&As[0][(w << 3)     ][0];
    auto lA_0_1 = (AS3 void*)&As[0][(w << 3) + 32][0];
    auto lA_1_0 = (AS3 void*)&As[1][(w << 3)     ][0];
    auto lA_1_1 = (AS3 void*)&As[1][(w << 3) + 32][0];
    auto lB_0_0 = (AS3 void*)&Bs[0][(w << 3)     ][0];
    auto lB_0_1 = (AS3 void*)&Bs[0][(w << 3) + 32][0];
    auto lB_0_2 = (AS3 void*)&Bs[0][(w << 3) + 64][0];
    auto lB_0_3 = (AS3 void*)&Bs[0][(w << 3) + 96][0];
    auto lB_1_0 = (AS3 void*)&Bs[1][(w << 3)     ][0];
    auto lB_1_1 = (AS3 void*)&Bs[1][(w << 3) + 32][0];
    auto lB_1_2 = (AS3 void*)&Bs[1][(w << 3) + 64][0];
    auto lB_1_3 = (AS3 void*)&Bs[1][(w << 3) + 96][0];

    // ---- fragment read addresses ----
    int mlane = l & 15, qlane = l >> 4;
    int wm = w >> 1, wn = w & 1;
    int c0 = (qlane ^ (mlane & 7)) << 3;   // k-chunk 0..3 (shorts, swizzled)
    int c1 = c0 ^ 32;                      // k-chunk 4..7
    int am0 = wm * 32 + mlane, am1 = am0 + 16;
    int bn0 = wn * 64 + mlane, bn1 = bn0 + 16, bn2 = bn0 + 32, bn3 = bn0 + 48;

    f32x4 acc[2][4] = {};

    STAGE(0);
    __syncthreads();
    constexpr int NT = K / BKU;            // 32 (down) or 4 (up)
#pragma unroll 1
    for (int t = 0; t < NT; t += 2) {
        if (t + 1 < NT) STAGE(1);
        COMP(0);
        __syncthreads();
        if (t + 2 < NT) STAGE(0);
        COMP(1);
        __syncthreads();
    }

    // epilogue: D layout col = lane&15, row = (lane>>4)*4 + reg  [m89-verified]
#pragma unroll
    for (int i = 0; i < 2; i++) {
        int rbase = row0 + wm * 32 + i * 16 + qlane * 4;
#pragma unroll
        for (int j = 0; j < 4; j++) {
            int col = n0 + wn * 64 + j * 16 + mlane;
#pragma unroll
            for (int r = 0; r < 4; r++)
                C[(size_t)(rbase + r) * Ntot + col] = f2bf(acc[i][j][r]);
        }
    }
}

#undef STAGE
#undef COMP
#undef AS3

// ---------------------------------------------------------------------------
// Combine down rows -> per-token down (fp32 gates), emit bf16 for up GEMM.
// ---------------------------------------------------------------------------
__global__ __launch_bounds__(256) void combine1_kernel(const short* __restrict__ dr,
                                                       const int* __restrict__ rowpos,
                                                       const float* __restrict__ gval,
                                                       short* __restrict__ dt)
{
    int t = blockIdx.x, d = threadIdx.x;
    int   p0 = rowpos[2 * t], p1 = rowpos[2 * t + 1];
    float g0 = gval[2 * t],   g1 = gval[2 * t + 1];
    float v = g0 * b2f(dr[(size_t)p0 * DG + d]) + g1 * b2f(dr[(size_t)p1 * DG + d]);
    dt[(size_t)t * DG + d] = f2bf(v);
}

// ---------------------------------------------------------------------------
// Combine up rows -> final output (fp32). short4-vectorized.
// ---------------------------------------------------------------------------
__global__ __launch_bounds__(256) void combine2_kernel(const short* __restrict__ ur,
                                                       const int* __restrict__ rowpos,
                                                       const float* __restrict__ gval,
                                                       float* __restrict__ out)
{
    int i = blockIdx.x * 256 + threadIdx.x;       // i < T*D/4
    int t = i >> 9;                               // D/4 = 512
    int c = (i & 511) * 4;
    int   p0 = rowpos[2 * t], p1 = rowpos[2 * t + 1];
    float g0 = gval[2 * t],   g1 = gval[2 * t + 1];
    short4 u0 = *(const short4*)&ur[(size_t)p0 * DIM + c];
    short4 u1 = *(const short4*)&ur[(size_t)p1 * DIM + c];
    float4 o;
    o.x = g0 * b2f(u0.x) + g1 * b2f(u1.x);
    o.y = g0 * b2f(u0.y) + g1 * b2f(u1.y);
    o.z = g0 * b2f(u0.z) + g1 * b2f(u1.z);
    o.w = g0 * b2f(u0.w) + g1 * b2f(u1.w);
    *(float4*)&out[(size_t)t * DIM + c] = o;
}

extern "C" void kernel_launch(void* const* d_in, const int* in_sizes, int n_in,
                              void* d_out, int out_size, void* d_ws, size_t ws_size,
                              hipStream_t stream) {
    const float* x  = (const float*)d_in[0];
    const float* Wg = (const float*)d_in[1];
    const float* Wd = (const float*)d_in[2];
    const float* Wu = (const float*)d_in[3];
    float* out = (float*)d_out;

    char* p = (char*)d_ws;
    int*   gidx    = (int*)(p + 0);                       // 32768
    float* gval    = (float*)(p + 32768);                 // 32768
    int*   rowtok  = (int*)(p + 65536);                   // 34816
    int*   rowpos  = (int*)(p + 100352);                  // 32768
    int*   seg_off = (int*)(p + 133120);                  // 256 (padded)
    short* x_bf    = (short*)(p + 133376);                // 16777216
    short* Wd_bf   = (short*)(p + 133376 + 16777216);     // 8388608
    short* Wu_bf   = Wd_bf + 4194304;                     // 8388608
    short* dr_bf   = Wu_bf + 4194304;                     // NROWS*DG*2  = 4456448
    short* dt_bf   = dr_bf + (size_t)NROWS * DG;          // T*DG*2      = 2097152
    short* ur_bf   = dt_bf + (size_t)T_TOK * DG;          // NROWS*DIM*2 = 35651584

    const int W4 = NEXP * DG * DIM / 4;   // 1048576 float4 per weight tensor
    gate_kernel<<<T_TOK / 4, 256, 0, stream>>>(x, Wg, gidx, gval, x_bf);
    convW_kernel<<<(2 * W4 + 255) / 256, 256, 0, stream>>>(Wd, Wu, Wd_bf, Wu_bf, W4);
    bucket_kernel<<<1, 1024, 0, stream>>>(gidx, rowtok, rowpos, seg_off);

    gemm_kernel<DIM, DG><<<dim3(NBLK_M, DG / BN), 256, 0, stream>>>(x_bf, Wd_bf, rowtok, seg_off, dr_bf);
    combine1_kernel<<<T_TOK, 256, 0, stream>>>(dr_bf, rowpos, gval, dt_bf);
    gemm_kernel<DG, DIM><<<dim3(NBLK_M, DIM / BN), 256, 0, stream>>>(dt_bf, Wu_bf, rowtok, seg_off, ur_bf);
    combine2_kernel<<<T_TOK * DIM / 4 / 256, 256, 0, stream>>>(ur_bf, rowpos, gval, out);
}